// Round 1
// baseline (427.346 us; speedup 1.0000x reference)
//
#include <hip/hip_runtime.h>
#include <hip/hip_bf16.h>
#include <stdint.h>

// ---------------------------------------------------------------------------
// GSVD layer: y = x @ (U diag(S) Vh)^T, factored as
//   t = x @ (S*Vh)^T   [M=8192, R=1024],  K=4096
//   y = t @ U^T        [M=8192, O=4096],  K=1024
// bf16 MFMA (16x16x32), fp32 accumulate. 137 GFLOP total vs 309 direct.
// ---------------------------------------------------------------------------

typedef __attribute__((ext_vector_type(8))) __bf16 bf16x8;
typedef __attribute__((ext_vector_type(4))) float f32x4;

#define AS1(p) ((const __attribute__((address_space(1))) void*)(p))
#define AS3(p) ((__attribute__((address_space(3))) void*)(p))

static __device__ __forceinline__ unsigned short f2bf(float f) {
  union { float f; unsigned int u; } c; c.f = f;
  unsigned int u = c.u;
  // round-to-nearest-even (inputs finite; no NaN handling needed)
  return (unsigned short)((u + 0x7FFFu + ((u >> 16) & 1u)) >> 16);
}

// fp32 -> bf16 cast, 4 elems/thread (n4 = n/4)
__global__ void cast_bf16_k(const float* __restrict__ in,
                            unsigned short* __restrict__ out, int n4) {
  int gid = blockIdx.x * blockDim.x + threadIdx.x;
  if (gid >= n4) return;
  const float4 v = ((const float4*)in)[gid];
  ushort4 o;
  o.x = f2bf(v.x); o.y = f2bf(v.y); o.z = f2bf(v.z); o.w = f2bf(v.w);
  ((ushort4*)out)[gid] = o;
}

// Vs[r][i] = bf16(S[r] * Vh[r][i]); din4 = D_IN/4
__global__ void scale_cast_k(const float* __restrict__ Vh,
                             const float* __restrict__ S,
                             unsigned short* __restrict__ out,
                             int n4, int din4) {
  int gid = blockIdx.x * blockDim.x + threadIdx.x;
  if (gid >= n4) return;
  float s = S[gid / din4];
  const float4 v = ((const float4*)Vh)[gid];
  ushort4 o;
  o.x = f2bf(v.x * s); o.y = f2bf(v.y * s);
  o.z = f2bf(v.z * s); o.w = f2bf(v.w * s);
  ((ushort4*)out)[gid] = o;
}

// ---------------------------------------------------------------------------
// C[m,n] = sum_k A[m,k] * B[n,k]   (A:[M,K] bf16 rm, B:[N,K] bf16 rm)
// 128x128 tile, BK=32, 256 threads = 4 waves in 2x2, each wave 64x64 via
// 4x4 grid of 16x16x32 MFMAs. global_load_lds width=16 staging (m97 pattern).
// M,N % 128 == 0; K % 32 == 0 (all guaranteed by the problem shapes).
// ---------------------------------------------------------------------------
template <bool OUT_BF16>
__global__ __launch_bounds__(256)
void gemm_bt(const __bf16* __restrict__ A, const __bf16* __restrict__ B,
             void* __restrict__ C, int M, int N, int K) {
  __shared__ __bf16 As[128 * 32];
  __shared__ __bf16 Bs[128 * 32];

  const int t    = threadIdx.x;
  const int lane = t & 63;
  const int wid  = __builtin_amdgcn_readfirstlane(t >> 6);

  const int bm = blockIdx.x;
  const int bn = blockIdx.y;

  // staging: thread t loads 8 bf16 (16B) from row (t>>2), cols (t&3)*8..+7;
  // two rounds of 64 rows each cover the 128-row tile.
  const int srow = t >> 2;
  const int scol = (t & 3) << 3;
  const __bf16* gA = A + (size_t)(bm * 128 + srow) * K + scol;
  const __bf16* gB = B + (size_t)(bn * 128 + srow) * K + scol;
  const size_t rowskip = (size_t)64 * K;

  // wave-uniform LDS bases; lane l lands at base + l*16B which equals
  // row-major [row][k8] with row = (roundbase + wid*16 + (l>>2)), k8=(l&3)*8
  __bf16* ldsA = &As[(wid * 16) * 32];
  __bf16* ldsB = &Bs[(wid * 16) * 32];

  const int wm = (wid >> 1) * 64;  // wave sub-tile origin
  const int wn = (wid & 1) * 64;
  const int q  = lane >> 4;        // quad (k-group)
  const int lr = lane & 15;        // row (A) / col (B) within 16

  f32x4 acc[4][4] = {};

  for (int k0 = 0; k0 < K; k0 += 32) {
    __syncthreads();  // previous tile's ds_reads done before overwrite
    __builtin_amdgcn_global_load_lds(AS1(gA + k0),           AS3(ldsA),           16, 0, 0);
    __builtin_amdgcn_global_load_lds(AS1(gA + k0 + rowskip), AS3(ldsA + 64 * 32), 16, 0, 0);
    __builtin_amdgcn_global_load_lds(AS1(gB + k0),           AS3(ldsB),           16, 0, 0);
    __builtin_amdgcn_global_load_lds(AS1(gB + k0 + rowskip), AS3(ldsB + 64 * 32), 16, 0, 0);
    __syncthreads();  // compiler emits vmcnt(0) drain before s_barrier

    bf16x8 af[4], bfr[4];
#pragma unroll
    for (int i = 0; i < 4; ++i)
      af[i] = *(const bf16x8*)&As[(wm + i * 16 + lr) * 32 + q * 8];
#pragma unroll
    for (int j = 0; j < 4; ++j)
      bfr[j] = *(const bf16x8*)&Bs[(wn + j * 16 + lr) * 32 + q * 8];

#pragma unroll
    for (int i = 0; i < 4; ++i)
#pragma unroll
      for (int j = 0; j < 4; ++j)
        acc[i][j] = __builtin_amdgcn_mfma_f32_16x16x32_bf16(af[i], bfr[j],
                                                            acc[i][j], 0, 0, 0);
  }

  // C/D layout: col = lane&15, row = (lane>>4)*4 + reg   [m89/m91 verified]
  const int r0 = q * 4;
#pragma unroll
  for (int i = 0; i < 4; ++i) {
#pragma unroll
    for (int j = 0; j < 4; ++j) {
      const int col = bn * 128 + wn + j * 16 + lr;
#pragma unroll
      for (int r = 0; r < 4; ++r) {
        const int row = bm * 128 + wm + i * 16 + r0 + r;
        const float v = acc[i][j][r];
        if (OUT_BF16) {
          ((unsigned short*)C)[(size_t)row * N + col] = f2bf(v);
        } else {
          ((float*)C)[(size_t)row * N + col] = v;
        }
      }
    }
  }
}

extern "C" void kernel_launch(void* const* d_in, const int* in_sizes, int n_in,
                              void* d_out, int out_size, void* d_ws, size_t ws_size,
                              hipStream_t stream) {
  const float* x  = (const float*)d_in[0];  // [4,2048,4096] = [8192,4096]
  const float* U  = (const float*)d_in[1];  // [4096,1024]
  const float* S  = (const float*)d_in[2];  // [1024]
  const float* Vh = (const float*)d_in[3];  // [1024,4096]
  float* y = (float*)d_out;                 // [8192,4096] fp32

  const int M = 8192, DIN = 4096, DOUT = 4096, R = 1024;

  char* ws = (char*)d_ws;
  unsigned short* xb = (unsigned short*)(ws);              // 67108864 B  x  bf16
  unsigned short* vs = (unsigned short*)(ws + 67108864);   //  8388608 B  S*Vh bf16
  unsigned short* ub = (unsigned short*)(ws + 75497472);   //  8388608 B  U  bf16
  unsigned short* tb = (unsigned short*)(ws + 83886080);   // 16777216 B  t  bf16

  cast_bf16_k<<<(M * DIN / 4 + 255) / 256, 256, 0, stream>>>(x, xb, M * DIN / 4);
  cast_bf16_k<<<(DOUT * R / 4 + 255) / 256, 256, 0, stream>>>(U, ub, DOUT * R / 4);
  scale_cast_k<<<(R * DIN / 4 + 255) / 256, 256, 0, stream>>>(Vh, S, vs,
                                                              R * DIN / 4, DIN / 4);

  // t = x @ (S*Vh)^T : [8192,1024], K=4096, bf16 out
  gemm_bt<true><<<dim3(M / 128, R / 128), 256, 0, stream>>>(
      (const __bf16*)xb, (const __bf16*)vs, tb, M, R, DIN);

  // y = t @ U^T : [8192,4096], K=1024, fp32 out
  gemm_bt<false><<<dim3(M / 128, DOUT / 128), 256, 0, stream>>>(
      (const __bf16*)tb, (const __bf16*)ub, y, M, DOUT, R);
}